// Round 4
// baseline (325.667 us; speedup 1.0000x reference)
//
#include <hip/hip_runtime.h>
#include <hip/hip_bf16.h>

// Problem constants
#define NB   32
#define NT   128
#define NK   128
#define NCP  62            // NC - NKH + 1
#define BN_EPS 1e-3f
#define NBT  8             // bt slices per block

typedef __attribute__((ext_vector_type(8))) short short8;
typedef __attribute__((ext_vector_type(4))) float floatx4;

__device__ __forceinline__ short f2bf(float f) {
    __hip_bfloat16 h = __float2bfloat16(f);
    return *reinterpret_cast<short*>(&h);
}

// Prep: B fragments in exact wave-load order + per-t BN (scale, shift).
// bfrag[(nt*6+s)*64 + lane], lane=(q<<4)|col holds 8 bf16 of w[j][n],
// j = s*32 + q*8 .. +7, n = nt*16 + col.  (3072 chunks = 48 KB)
__global__ __launch_bounds__(256) void prep(
    const float* __restrict__ w, const float* __restrict__ gamma,
    const float* __restrict__ beta, const float* __restrict__ mean,
    const float* __restrict__ var, short8* __restrict__ bfrag,
    float2* __restrict__ ss)
{
    int idx  = blockIdx.x * 256 + threadIdx.x;   // 0..3071
    int lane = idx & 63;
    int ts   = idx >> 6;
    int nt   = ts / 6;
    int s    = ts - nt * 6;
    int col  = lane & 15, q = lane >> 4;
    int n    = nt * 16 + col;
    int j0   = s * 32 + q * 8;
    short8 p;
    #pragma unroll
    for (int e = 0; e < 8; ++e) p[e] = f2bf(w[(size_t)(j0 + e) * NK + n]);
    bfrag[idx] = p;
    if (idx < NT) {
        float sc = gamma[idx] * rsqrtf(var[idx] + BN_EPS);
        ss[idx] = make_float2(sc, beta[idx] - mean[idx] * sc);
    }
}

// Main: 512 threads = 8 waves; wave wv owns n-tile wv (cols 16wv..16wv+15),
// B fragments pinned in registers, loop over NBT bt slices x 4 m-tiles.
__global__ __launch_bounds__(512, 4) void tccnn_mfma3(
    const float* __restrict__ x, const short8* __restrict__ bfrag,
    const float* __restrict__ bias, const float2* __restrict__ ss,
    float* __restrict__ out)
{
    const int tid  = threadIdx.x;
    const int wv   = tid >> 6;                   // n-tile index 0..7
    const int lane = tid & 63;
    const int col  = lane & 15;
    const int q    = lane >> 4;
    const int bt0  = blockIdx.x * NBT;

    // B fragments: loaded once, live in VGPRs for the whole kernel (24 VGPRs)
    short8 b[6];
    #pragma unroll
    for (int s = 0; s < 6; ++s) b[s] = bfrag[(wv * 6 + s) * 64 + lane];

    const float bv = bias[wv * 16 + col];        // this lane's output column bias

    const float4* xg  = (const float4*)x;
    const long   maxi = (long)NB * NT * 256 * 4 / 4 * 4;  // placeholder, set below
    const long   maxi4 = (long)NB * NT * 1024 - 2;        // last valid float4 pair base

    for (int i = 0; i < NBT; ++i) {
        const int bt = bt0 + i;
        const float2 sshift = ss[bt & (NT - 1)];

        #pragma unroll 2
        for (int mt = 0; mt < 4; ++mt) {
            // ---- A fragments: L1-hot coalesced f32 loads + register cvt ----
            const int row = mt * 16 + col;       // cp row 0..63
            long base4 = (long)bt * 1024 + row * 16 + q * 2;
            short8 a[6];
            #pragma unroll
            for (int s = 0; s < 6; ++s) {
                long i0 = base4 + s * 8;
                i0 = i0 > maxi4 ? maxi4 : i0;    // clamp rows 62/63 tail
                float4 v0 = xg[i0];
                float4 v1 = xg[i0 + 1];
                short8 p;
                p[0] = f2bf(v0.x); p[1] = f2bf(v0.y); p[2] = f2bf(v0.z); p[3] = f2bf(v0.w);
                p[4] = f2bf(v1.x); p[5] = f2bf(v1.y); p[6] = f2bf(v1.z); p[7] = f2bf(v1.w);
                a[s] = p;
            }

            floatx4 acc = (floatx4){0.f, 0.f, 0.f, 0.f};
            #pragma unroll
            for (int s = 0; s < 6; ++s)
                acc = __builtin_amdgcn_mfma_f32_16x16x32_bf16(a[s], b[s], acc, 0, 0, 0);

            // ---- epilogue: bias + BN + relu, guarded stores ----
            float* ob = out + (size_t)bt * (NCP * NK) + wv * 16 + col;
            #pragma unroll
            for (int reg = 0; reg < 4; ++reg) {
                const int cp = mt * 16 + q * 4 + reg;
                if (cp < NCP) {
                    float v = (acc[reg] + bv) * sshift.x + sshift.y;
                    ob[(size_t)cp * NK] = v > 0.f ? v : 0.f;
                }
            }
        }
    }
    (void)maxi;
}

extern "C" void kernel_launch(void* const* d_in, const int* in_sizes, int n_in,
                              void* d_out, int out_size, void* d_ws, size_t ws_size,
                              hipStream_t stream) {
    const float* x     = (const float*)d_in[0];
    const float* w     = (const float*)d_in[1];
    const float* bias  = (const float*)d_in[2];
    const float* gamma = (const float*)d_in[3];
    const float* beta  = (const float*)d_in[4];
    const float* mean  = (const float*)d_in[5];
    const float* var   = (const float*)d_in[6];
    float* out = (float*)d_out;

    short8* bfrag = (short8*)d_ws;                         // 48 KB
    float2* ss    = (float2*)((char*)d_ws + 3072 * 16);    // 1 KB @ +48 KB

    prep<<<dim3(12), dim3(256), 0, stream>>>(w, gamma, beta, mean, var, bfrag, ss);
    tccnn_mfma3<<<dim3(NB * NT / NBT), dim3(512), 0, stream>>>(
        x, bfrag, bias, ss, out);
}

// Round 5
// 320.373 us; speedup vs baseline: 1.0165x; 1.0165x over previous
//
#include <hip/hip_runtime.h>
#include <hip/hip_bf16.h>

// Problem constants
#define NB   32
#define NT   128
#define NK   128
#define NCP  62            // NC - NKH + 1
#define BN_EPS 1e-3f
#define SPB  8             // bt slices per block
#define NIT  (SPB * 4)     // 4 m-tiles per slice

typedef __attribute__((ext_vector_type(8))) short short8;
typedef __attribute__((ext_vector_type(4))) float floatx4;

__device__ __forceinline__ short f2bf(float f) {
    __hip_bfloat16 h = __float2bfloat16(f);
    return *reinterpret_cast<short*>(&h);
}

// Prep: B fragments in wave-load order + per-t BN (scale, shift).
// bfrag[(nt*6+s)*64 + lane], lane=(q<<4)|col holds 8 bf16 of w[j][n],
// j = s*32 + q*8 .. +7, n = nt*16 + col.  (3072 chunks = 48 KB)
__global__ __launch_bounds__(256) void prep(
    const float* __restrict__ w, const float* __restrict__ gamma,
    const float* __restrict__ beta, const float* __restrict__ mean,
    const float* __restrict__ var, short8* __restrict__ bfrag,
    float2* __restrict__ ss)
{
    int idx  = blockIdx.x * 256 + threadIdx.x;   // 0..3071
    int lane = idx & 63;
    int ts   = idx >> 6;
    int nt   = ts / 6;
    int s    = ts - nt * 6;
    int col  = lane & 15, q = lane >> 4;
    int n    = nt * 16 + col;
    int j0   = s * 32 + q * 8;
    short8 p;
    #pragma unroll
    for (int e = 0; e < 8; ++e) p[e] = f2bf(w[(size_t)(j0 + e) * NK + n]);
    bfrag[idx] = p;
    if (idx < NT) {
        float sc = gamma[idx] * rsqrtf(var[idx] + BN_EPS);
        ss[idx] = make_float2(sc, beta[idx] - mean[idx] * sc);
    }
}

// Main: 512 threads = 8 waves; wave wv owns n-tile wv (cols 16wv..16wv+15).
// B staged in LDS once per block; block loops 8 slices x 4 m-tiles with
// depth-1 A prefetch (raw float4 ring, cvt at use).
__global__ __launch_bounds__(512, 4) void tccnn_mfma4(
    const float* __restrict__ x, const short8* __restrict__ bfrag,
    const float* __restrict__ bias, const float2* __restrict__ ss,
    float* __restrict__ out)
{
    __shared__ short8 bsh[3072];                 // 48 KB

    const int tid  = threadIdx.x;
    const int wv   = tid >> 6;                   // n-tile 0..7
    const int lane = tid & 63;
    const int col  = lane & 15;
    const int q    = lane >> 4;

    // stage B (contiguous b128 copies, conflict-free)
    #pragma unroll
    for (int i = 0; i < 6; ++i) bsh[tid + i * 512] = bfrag[tid + i * 512];
    __syncthreads();

    // this wave's B fragments (LDS-resident; cheap to re-read if not pinned)
    short8 b[6];
    #pragma unroll
    for (int s = 0; s < 6; ++s) b[s] = bsh[(wv * 6 + s) * 64 + lane];

    const float bv = bias[wv * 16 + col];

    const float4* xg   = (const float4*)x;
    const long maxi4   = (long)NB * NT * 1024 - 2;  // clamp for bt=4095 rows 62/63
    const int  bt0     = blockIdx.x * SPB;

    // depth-1 prefetch ring
    float4 raw[12];
    {   // iteration 0: slice bt0, m-tile 0
        long base4 = (long)bt0 * 1024 + col * 16 + q * 2;
        #pragma unroll
        for (int s = 0; s < 6; ++s) {
            long i0 = base4 + s * 8;
            i0 = i0 > maxi4 ? maxi4 : i0;
            raw[2 * s] = xg[i0]; raw[2 * s + 1] = xg[i0 + 1];
        }
    }

    #pragma unroll 1
    for (int it = 0; it < NIT; ++it) {
        const int sl = it >> 2, mt = it & 3;
        const int bt = bt0 + sl;

        // convert current raw -> bf16 A fragments (waits on the prefetch)
        short8 a[6];
        #pragma unroll
        for (int s = 0; s < 6; ++s) {
            float4 v0 = raw[2 * s], v1 = raw[2 * s + 1];
            short8 p;
            p[0] = f2bf(v0.x); p[1] = f2bf(v0.y); p[2] = f2bf(v0.z); p[3] = f2bf(v0.w);
            p[4] = f2bf(v1.x); p[5] = f2bf(v1.y); p[6] = f2bf(v1.z); p[7] = f2bf(v1.w);
            a[s] = p;
        }

        // issue next iteration's loads (WAR on raw keeps them after the cvt)
        if (it + 1 < NIT) {
            const int nit = it + 1, nsl = nit >> 2, nmt = nit & 3;
            long base4 = (long)(bt0 + nsl) * 1024 + (nmt * 16 + col) * 16 + q * 2;
            #pragma unroll
            for (int s = 0; s < 6; ++s) {
                long i0 = base4 + s * 8;
                i0 = i0 > maxi4 ? maxi4 : i0;
                raw[2 * s] = xg[i0]; raw[2 * s + 1] = xg[i0 + 1];
            }
        }

        floatx4 acc = (floatx4){0.f, 0.f, 0.f, 0.f};
        #pragma unroll
        for (int s = 0; s < 6; ++s)
            acc = __builtin_amdgcn_mfma_f32_16x16x32_bf16(a[s], b[s], acc, 0, 0, 0);

        // epilogue: bias + BN + relu
        const float2 sshift = ss[bt & (NT - 1)];
        const float sc = sshift.x;
        const float sh = bv * sc + sshift.y;
        float* ob = out + (size_t)bt * (NCP * NK) + wv * 16 + col;
        #pragma unroll
        for (int reg = 0; reg < 4; ++reg) {
            const int cp = mt * 16 + q * 4 + reg;
            if (cp < NCP) {
                float v = acc[reg] * sc + sh;
                ob[(size_t)cp * NK] = v > 0.f ? v : 0.f;
            }
        }
    }
}

extern "C" void kernel_launch(void* const* d_in, const int* in_sizes, int n_in,
                              void* d_out, int out_size, void* d_ws, size_t ws_size,
                              hipStream_t stream) {
    const float* x     = (const float*)d_in[0];
    const float* w     = (const float*)d_in[1];
    const float* bias  = (const float*)d_in[2];
    const float* gamma = (const float*)d_in[3];
    const float* beta  = (const float*)d_in[4];
    const float* mean  = (const float*)d_in[5];
    const float* var   = (const float*)d_in[6];
    float* out = (float*)d_out;

    short8* bfrag = (short8*)d_ws;                         // 48 KB
    float2* ss    = (float2*)((char*)d_ws + 3072 * 16);    // 1 KB @ +48 KB

    prep<<<dim3(12), dim3(256), 0, stream>>>(w, gamma, beta, mean, var, bfrag, ss);
    tccnn_mfma4<<<dim3(NB * NT / SPB), dim3(512), 0, stream>>>(
        x, bfrag, bias, ss, out);
}

// Round 6
// 193.441 us; speedup vs baseline: 1.6835x; 1.6562x over previous
//
#include <hip/hip_runtime.h>
#include <hip/hip_bf16.h>

// Problem constants
#define NB   32
#define NT   128
#define NK   128
#define NCP  62            // NC - KH + 1
#define BN_EPS 1e-3f
#define SPB  8             // bt slices per block
#define XCH  576           // chunks per x buffer: 512 data + 64 pad (rows 62/63 overrun)

typedef __attribute__((ext_vector_type(8))) short short8;
typedef __attribute__((ext_vector_type(4))) float floatx4;

__device__ __forceinline__ short f2bf(float f) {
    __hip_bfloat16 h = __float2bfloat16(f);
    return *reinterpret_cast<short*>(&h);
}

__device__ __forceinline__ short8 pack8(float4 v0, float4 v1) {
    short8 p;
    p[0] = f2bf(v0.x); p[1] = f2bf(v0.y); p[2] = f2bf(v0.z); p[3] = f2bf(v0.w);
    p[4] = f2bf(v1.x); p[5] = f2bf(v1.y); p[6] = f2bf(v1.z); p[7] = f2bf(v1.w);
    return p;
}

// chunk swizzle (verified conflict-free in round 2 for this A-read pattern)
__device__ __forceinline__ int swz(int c) { return c ^ ((c >> 3) & 7); }

// Prep: B fragments in wave-load order + per-t BN (scale, shift).
// bfrag[(nt*6+s)*64 + lane], lane=(q<<4)|col holds 8 bf16 of w[j][n],
// j = s*32 + q*8 .. +7, n = nt*16 + col.  (3072 chunks = 48 KB)
__global__ __launch_bounds__(256) void prep(
    const float* __restrict__ w, const float* __restrict__ gamma,
    const float* __restrict__ beta, const float* __restrict__ mean,
    const float* __restrict__ var, short8* __restrict__ bfrag,
    float2* __restrict__ ss)
{
    int idx  = blockIdx.x * 256 + threadIdx.x;   // 0..3071
    int lane = idx & 63;
    int ts   = idx >> 6;
    int nt   = ts / 6;
    int s    = ts - nt * 6;
    int col  = lane & 15, q = lane >> 4;
    int n    = nt * 16 + col;
    int j0   = s * 32 + q * 8;
    short8 p;
    #pragma unroll
    for (int e = 0; e < 8; ++e) p[e] = f2bf(w[(size_t)(j0 + e) * NK + n]);
    bfrag[idx] = p;
    if (idx < NT) {
        float sc = gamma[idx] * rsqrtf(var[idx] + BN_EPS);
        ss[idx] = make_float2(sc, beta[idx] - mean[idx] * sc);
    }
}

// Main: 512 threads = 8 waves. B in LDS once per block (8 slices).
// Wave (mh, a2) owns m-tiles {mh,mh+1} x n-tiles {a2,a2+1}.
// x double-buffered in LDS (bf16, swizzled); depth-1 slice prefetch in 8 regs.
__global__ __launch_bounds__(512, 4) void tccnn_mfma5(
    const float* __restrict__ x, const short8* __restrict__ bfrag,
    const float* __restrict__ bias, const float2* __restrict__ ss,
    float* __restrict__ out)
{
    __shared__ short8 bsh[3072];        // 48 KB
    __shared__ short8 xsh[2][XCH];      // 18 KB

    const int tid  = threadIdx.x;
    const int wv   = tid >> 6;
    const int lane = tid & 63;
    const int col  = lane & 15;
    const int q    = lane >> 4;
    const int a2   = (wv & 3) * 2;      // first n-tile (0,2,4,6)
    const int mh   = (wv >> 2) * 2;     // first m-tile (0 or 2)
    const int bt0  = blockIdx.x * SPB;

    // ---- stage B (contiguous b128 copies) ----
    #pragma unroll
    for (int i = 0; i < 6; ++i) bsh[tid + i * 512] = bfrag[tid + i * 512];

    // ---- prologue: slice 0 -> xbuf[0]; prefetch slice 1 into regs ----
    const float4* xg = (const float4*)(x + (size_t)bt0 * 4096);
    float4 r0 = xg[2 * tid], r1 = xg[2 * tid + 1];
    xsh[0][swz(tid)] = pack8(r0, r1);
    r0 = xg[1024 + 2 * tid]; r1 = xg[1024 + 2 * tid + 1];
    __syncthreads();

    // ---- this wave's B fragments (target: pinned in 48 VGPRs) ----
    short8 b[2][6];
    #pragma unroll
    for (int ni = 0; ni < 2; ++ni)
        #pragma unroll
        for (int s = 0; s < 6; ++s)
            b[ni][s] = bsh[((a2 + ni) * 6 + s) * 64 + lane];

    const float bv0 = bias[(a2 + 0) * 16 + col];
    const float bv1 = bias[(a2 + 1) * 16 + col];

    for (int sl = 0; sl < SPB; ++sl) {
        const int p  = sl & 1;
        const int bt = bt0 + sl;
        const float2 sshift = ss[bt & (NT - 1)];
        const float sc = sshift.x;
        const float sh0 = bv0 * sc + sshift.y;
        const float sh1 = bv1 * sc + sshift.y;

        float* ob = out + (size_t)bt * (NCP * NK);
        #pragma unroll
        for (int mi = 0; mi < 2; ++mi) {
            const int mt  = mh + mi;
            const int row = mt * 16 + col;

            short8 a[6];
            #pragma unroll
            for (int s = 0; s < 6; ++s)
                a[s] = xsh[p][swz(8 * row + 4 * s + q)];

            floatx4 acc0 = (floatx4){0.f, 0.f, 0.f, 0.f};
            floatx4 acc1 = (floatx4){0.f, 0.f, 0.f, 0.f};
            #pragma unroll
            for (int s = 0; s < 6; ++s) {
                acc0 = __builtin_amdgcn_mfma_f32_16x16x32_bf16(a[s], b[0][s], acc0, 0, 0, 0);
                acc1 = __builtin_amdgcn_mfma_f32_16x16x32_bf16(a[s], b[1][s], acc1, 0, 0, 0);
            }

            #pragma unroll
            for (int reg = 0; reg < 4; ++reg) {
                const int cp = mt * 16 + q * 4 + reg;
                if (cp < NCP) {
                    float v0 = acc0[reg] * sc + sh0;
                    float v1 = acc1[reg] * sc + sh1;
                    ob[(size_t)cp * NK + a2 * 16 + col]        = v0 > 0.f ? v0 : 0.f;
                    ob[(size_t)cp * NK + (a2 + 1) * 16 + col]  = v1 > 0.f ? v1 : 0.f;
                }
            }
        }

        // ---- stage slice sl+1 (regs were loaded a full slice ago); prefetch sl+2 ----
        if (sl + 1 < SPB) {
            xsh[p ^ 1][swz(tid)] = pack8(r0, r1);
            if (sl + 2 < SPB) {
                r0 = xg[(sl + 2) * 1024 + 2 * tid];
                r1 = xg[(sl + 2) * 1024 + 2 * tid + 1];
            }
        }
        __syncthreads();
    }
}

extern "C" void kernel_launch(void* const* d_in, const int* in_sizes, int n_in,
                              void* d_out, int out_size, void* d_ws, size_t ws_size,
                              hipStream_t stream) {
    const float* x     = (const float*)d_in[0];
    const float* w     = (const float*)d_in[1];
    const float* bias  = (const float*)d_in[2];
    const float* gamma = (const float*)d_in[3];
    const float* beta  = (const float*)d_in[4];
    const float* mean  = (const float*)d_in[5];
    const float* var   = (const float*)d_in[6];
    float* out = (float*)d_out;

    short8* bfrag = (short8*)d_ws;                         // 48 KB
    float2* ss    = (float2*)((char*)d_ws + 3072 * 16);    // 1 KB @ +48 KB

    prep<<<dim3(12), dim3(256), 0, stream>>>(w, gamma, beta, mean, var, bfrag, ss);
    tccnn_mfma5<<<dim3(NB * NT / SPB), dim3(512), 0, stream>>>(
        x, bfrag, bias, ss, out);
}